// Round 4
// baseline (376.933 us; speedup 1.0000x reference)
//
#include <hip/hip_runtime.h>

// UltralyticsDetect head, fused: per-level 1x1-conv GEMM (M=144, K=C, N=B*HW)
// in bf16 MFMA + in-register DFL softmax decode + output assembly.
// Output: (16, 8400, 84) f32.
//
// R4: register prefetch (T14) for BOTH X and W chunks (W-load latency was the
// exposed critical path per chunk); plain stores (NT stores caused 1.7x write
// amplification: 16B scattered chunks bypass L2 line merging).

typedef __bf16 bf16x8 __attribute__((ext_vector_type(8)));
typedef float  f32x4  __attribute__((ext_vector_type(4)));

#define NTHREADS 256

// round-half-up f32 -> bf16, pack two into one u32 (a -> low16, b -> high16)
__device__ __forceinline__ unsigned int pack_bf16(float a, float b) {
    unsigned int ua = __builtin_bit_cast(unsigned int, a);
    unsigned int ub = __builtin_bit_cast(unsigned int, b);
    return ((ua + 0x8000u) >> 16) | ((ub + 0x8000u) & 0xffff0000u);
}

// LDS tile: row-major [row][64 bf16] = 128B rows, XOR-swizzled to kill the
// 32-way ds_read_b128 bank conflict (G4: byte ^= (row&7)<<4).
__device__ __forceinline__ int swz(int row, int kbyte) {
    return row * 128 + (kbyte ^ ((row & 7) << 4));
}

template <int LVL>
__device__ __forceinline__ void run_level(
        int rb,
        const float* __restrict__ x,
        const float* __restrict__ wbox, const float* __restrict__ bbox,
        const float* __restrict__ wcls, const float* __restrict__ bcls,
        float* __restrict__ out,
        unsigned char* s_w, unsigned char* s_x) {

    constexpr int   C      = (LVL == 0) ? 256 : 512;
    constexpr int   GW     = (LVL == 0) ? 80 : (LVL == 1 ? 40 : 20);
    constexpr int   HW     = GW * GW;
    constexpr int   AOFF   = (LVL == 0) ? 0 : (LVL == 1 ? 6400 : 8000);
    constexpr float STRIDE = (LVL == 0) ? 8.0f : (LVL == 1 ? 16.0f : 32.0f);
    constexpr int   TPB    = (HW + 63) / 64;   // 64-anchor tiles per image

    const int b    = rb / TPB;
    const int tile = rb % TPB;
    const int hw0  = tile * 64;
    const int nv   = (HW - hw0 < 64) ? (HW - hw0) : 64;  // valid anchors

    const int tid  = threadIdx.x;
    const int wv   = tid >> 6;        // wave 0..3
    const int lane = tid & 63;
    const int col  = lane & 15;       // MFMA n/col lane
    const int q4   = lane >> 4;       // MFMA row-quarter

    const float* xb = x + (size_t)b * C * HW;

    // X staging: thread -> (anchor = lane, k-group base = wave)
    const int anc  = lane;
    const int kgb  = wv;                              // 0..3
    const int ancc = (anc < nv) ? anc : (nv - 1);     // clamp OOB anchors
    const float* xcol = xb + hw0 + ancc;

    // W staging: thread -> units u = tid + i*256, u < 1152 ; row = u>>3, kg = u&7
    const float* wsrc[5];
#pragma unroll
    for (int i = 0; i < 5; ++i) {
        int u = tid + i * 256;
        if (u < 1152) {
            int row = u >> 3, kg = u & 7;
            wsrc[i] = ((row < 64) ? (wbox + row * C) : (wcls + (row - 64) * C)) + kg * 8;
        } else {
            wsrc[i] = nullptr;
        }
    }

    f32x4 acc[9];
#pragma unroll
    for (int m = 0; m < 9; ++m) acc[m] = (f32x4){0.f, 0.f, 0.f, 0.f};

    // ---- prologue: prefetch X and W chunk 0 into registers ----
    float xv[2][8];
#pragma unroll
    for (int i = 0; i < 2; ++i) {
        const float* p = xcol + (size_t)((kgb + 4 * i) * 8) * HW;
#pragma unroll
        for (int j = 0; j < 8; ++j) xv[i][j] = p[(size_t)j * HW];
    }
    float4 wvr[5][2];
#pragma unroll
    for (int i = 0; i < 5; ++i) {
        if (wsrc[i]) {
            wvr[i][0] = *(const float4*)(wsrc[i]);
            wvr[i][1] = *(const float4*)(wsrc[i] + 4);
        }
    }

    const int nkc = C / 64;
    for (int kc = 0; kc < nkc; ++kc) {
        __syncthreads();   // previous iteration's LDS reads complete

        // ---- pack prefetched W regs -> s_w (swizzled) ----
#pragma unroll
        for (int i = 0; i < 5; ++i) {
            int u = tid + i * 256;
            if (u < 1152) {
                int row = u >> 3, kg = u & 7;
                uint4 p;
                p.x = pack_bf16(wvr[i][0].x, wvr[i][0].y);
                p.y = pack_bf16(wvr[i][0].z, wvr[i][0].w);
                p.z = pack_bf16(wvr[i][1].x, wvr[i][1].y);
                p.w = pack_bf16(wvr[i][1].z, wvr[i][1].w);
                *(uint4*)(s_w + swz(row, kg * 16)) = p;
            }
        }

        // ---- pack prefetched X regs -> s_x (transposed [anchor][k]) ----
#pragma unroll
        for (int i = 0; i < 2; ++i) {
            const int kg = kgb + 4 * i;
            uint4 q;
            q.x = pack_bf16(xv[i][0], xv[i][1]);
            q.y = pack_bf16(xv[i][2], xv[i][3]);
            q.z = pack_bf16(xv[i][4], xv[i][5]);
            q.w = pack_bf16(xv[i][6], xv[i][7]);
            *(uint4*)(s_x + swz(anc, kg * 16)) = q;
        }

        // ---- issue next chunk's loads (latency hidden under MFMA phase) ----
        if (kc + 1 < nkc) {
            const int k0n = (kc + 1) * 64;
#pragma unroll
            for (int i = 0; i < 2; ++i) {
                const float* p = xcol + (size_t)(k0n + (kgb + 4 * i) * 8) * HW;
#pragma unroll
                for (int j = 0; j < 8; ++j) xv[i][j] = p[(size_t)j * HW];
            }
#pragma unroll
            for (int i = 0; i < 5; ++i) {
                if (wsrc[i]) {
                    wvr[i][0] = *(const float4*)(wsrc[i] + k0n);
                    wvr[i][1] = *(const float4*)(wsrc[i] + k0n + 4);
                }
            }
        }

        __syncthreads();

        // ---- MFMA: 2 k-steps of 32, 9 M-tiles x 1 N-tile per wave ----
#pragma unroll
        for (int ks = 0; ks < 2; ++ks) {
            const int kbyte = ks * 64 + q4 * 16;
            const bf16x8 bf = *(const bf16x8*)(s_x + swz(wv * 16 + col, kbyte));
#pragma unroll
            for (int m = 0; m < 9; ++m) {
                const bf16x8 af = *(const bf16x8*)(s_w + swz(m * 16 + col, kbyte));
                acc[m] = __builtin_amdgcn_mfma_f32_16x16x32_bf16(af, bf, acc[m], 0, 0, 0);
            }
        }
    }

    // ---- epilogue: in-register DFL decode + store ----
    // D layout (m89): value[r] = D[mtile*16 + q4*4 + r][col]
    float4 bcv[5];
#pragma unroll
    for (int m = 0; m < 5; ++m)
        bcv[m] = *(const float4*)(bcls + m * 16 + q4 * 4);

    const float LOG2E = 1.44269504088896f;

    const int alocal = wv * 16 + col;
    const bool valid = alocal < nv;
    const int hw = hw0 + alocal;

    float dist[4];
#pragma unroll
    for (int g = 0; g < 4; ++g) {
        const float4 bbv = *(const float4*)(bbox + g * 16 + q4 * 4);
        const float v0 = acc[g][0] + bbv.x;
        const float v1 = acc[g][1] + bbv.y;
        const float v2 = acc[g][2] + bbv.z;
        const float v3 = acc[g][3] + bbv.w;
        // softmax over 16 bins: 4 regs x 4 lanes (col, col+16, col+32, col+48)
        float mx = fmaxf(fmaxf(v0, v1), fmaxf(v2, v3));
        mx = fmaxf(mx, __shfl_xor(mx, 16));
        mx = fmaxf(mx, __shfl_xor(mx, 32));
        const float e0 = __builtin_amdgcn_exp2f((v0 - mx) * LOG2E);
        const float e1 = __builtin_amdgcn_exp2f((v1 - mx) * LOG2E);
        const float e2 = __builtin_amdgcn_exp2f((v2 - mx) * LOG2E);
        const float e3 = __builtin_amdgcn_exp2f((v3 - mx) * LOG2E);
        float s  = e0 + e1 + e2 + e3;
        float ws = e1 + 2.f * e2 + 3.f * e3 + (float)(q4 * 4) * s;
        s  += __shfl_xor(s, 16);
        s  += __shfl_xor(s, 32);
        ws += __shfl_xor(ws, 16);
        ws += __shfl_xor(ws, 32);
        dist[g] = ws / s;
    }

    if (valid) {
        const size_t obase = ((size_t)b * 8400 + AOFF + hw) * 84;
        if (q4 == 0) {
            const float ax = (float)(hw % GW) + 0.5f;
            const float ay = (float)(hw / GW) + 0.5f;
            f32x4 bx;
            bx[0] = (ax + 0.5f * (dist[2] - dist[0])) * STRIDE;
            bx[1] = (ay + 0.5f * (dist[3] - dist[1])) * STRIDE;
            bx[2] = (dist[0] + dist[2]) * STRIDE;
            bx[3] = (dist[1] + dist[3]) * STRIDE;
            *(f32x4*)(out + obase) = bx;
        }
#pragma unroll
        for (int m = 0; m < 5; ++m) {
            f32x4 v;
            v[0] = acc[m + 4][0] + bcv[m].x;
            v[1] = acc[m + 4][1] + bcv[m].y;
            v[2] = acc[m + 4][2] + bcv[m].z;
            v[3] = acc[m + 4][3] + bcv[m].w;
            *(f32x4*)(out + obase + 4 + m * 16 + q4 * 4) = v;
        }
    }
}

__global__ __launch_bounds__(NTHREADS, 4)
void UltralyticsDetect_kernel(
        const float* __restrict__ x0, const float* __restrict__ x1, const float* __restrict__ x2,
        const float* __restrict__ wb0, const float* __restrict__ bb0,
        const float* __restrict__ wc0, const float* __restrict__ bc0,
        const float* __restrict__ wb1, const float* __restrict__ bb1,
        const float* __restrict__ wc1, const float* __restrict__ bc1,
        const float* __restrict__ wb2, const float* __restrict__ bb2,
        const float* __restrict__ wc2, const float* __restrict__ bc2,
        float* __restrict__ out) {

    __shared__ __align__(16) unsigned char s_w[144 * 64 * 2];  // 18 KiB
    __shared__ __align__(16) unsigned char s_x[64 * 64 * 2];   //  8 KiB

    const int bid = blockIdx.x;
    // Long (K=512) levels first so the tail is filled by short level-0 blocks:
    // level 1: 16 b * 25 tiles = 400 ; level 2: 16*7 = 112 ; level 0: 16*100 = 1600
    if (bid < 400) {
        run_level<1>(bid, x1, wb1, bb1, wc1, bc1, out, s_w, s_x);
    } else if (bid < 512) {
        run_level<2>(bid - 400, x2, wb2, bb2, wc2, bc2, out, s_w, s_x);
    } else {
        run_level<0>(bid - 512, x0, wb0, bb0, wc0, bc0, out, s_w, s_x);
    }
}

extern "C" void kernel_launch(void* const* d_in, const int* in_sizes, int n_in,
                              void* d_out, int out_size, void* d_ws, size_t ws_size,
                              hipStream_t stream) {
    const float* x0  = (const float*)d_in[0];
    const float* x1  = (const float*)d_in[1];
    const float* x2  = (const float*)d_in[2];
    const float* wb0 = (const float*)d_in[3];
    const float* bb0 = (const float*)d_in[4];
    const float* wc0 = (const float*)d_in[5];
    const float* bc0 = (const float*)d_in[6];
    const float* wb1 = (const float*)d_in[7];
    const float* bb1 = (const float*)d_in[8];
    const float* wc1 = (const float*)d_in[9];
    const float* bc1 = (const float*)d_in[10];
    const float* wb2 = (const float*)d_in[11];
    const float* bb2 = (const float*)d_in[12];
    const float* wc2 = (const float*)d_in[13];
    const float* bc2 = (const float*)d_in[14];

    UltralyticsDetect_kernel<<<2112, NTHREADS, 0, stream>>>(
        x0, x1, x2,
        wb0, bb0, wc0, bc0,
        wb1, bb1, wc1, bc1,
        wb2, bb2, wc2, bc2,
        (float*)d_out);
}

// Round 5
// 55.192 us; speedup vs baseline: 6.8294x; 6.8294x over previous
//
#include <hip/hip_runtime.h>

// UltralyticsDetect head, fused: per-level 1x1-conv GEMM (M=144, K=C, N=B*HW)
// in bf16 MFMA + in-register DFL softmax decode + output assembly.
// Output: (16, 8400, 84) f32.
//
// R5: (a) revert W reg-prefetch (R4's 50-VGPR arrays spilled to scratch under
// the 128-cap: WRITE_SIZE 76->900 MB); (b) prep kernel pre-converts W to bf16
// PRE-SWIZZLED in d_ws, main loop stages W via global_load_lds width=16
// (linear LDS dest + pre-swizzled source, m173 pattern) -- no pack VALU, half
// the W bytes; (c) X next-chunk loads issued after barrier B so MFMA covers
// them; (d) __launch_bounds__(256,6): 6 blocks/CU (LDS 159.7KB, VGPR cap 85).

typedef __bf16 bf16x8 __attribute__((ext_vector_type(8)));
typedef float  f32x4  __attribute__((ext_vector_type(4)));

#define NTHREADS 256

// W image layout in d_ws: per level, C/64 chunks of 144 rows * 128 B,
// already swizzled; level byte offsets:
#define WOFF0 0
#define WOFF1 73728
#define WOFF2 221184
#define WCHUNK_BYTES 18432   // 144 * 128

// round-half-up f32 -> bf16, pack two into one u32 (a -> low16, b -> high16)
__device__ __forceinline__ unsigned int pack_bf16(float a, float b) {
    unsigned int ua = __builtin_bit_cast(unsigned int, a);
    unsigned int ub = __builtin_bit_cast(unsigned int, b);
    return ((ua + 0x8000u) >> 16) | ((ub + 0x8000u) & 0xffff0000u);
}

// LDS tile: row-major [row][64 bf16] = 128B rows, XOR-swizzled to kill the
// 32-way ds_read_b128 bank conflict (G4: byte ^= (row&7)<<4).
__device__ __forceinline__ int swz(int row, int kbyte) {
    return row * 128 + (kbyte ^ ((row & 7) << 4));
}

// async global->LDS, 16B per lane; LDS dest must be wave-uniform base + lane*16
__device__ __forceinline__ void gload_lds16(const void* g, void* l) {
    __builtin_amdgcn_global_load_lds(
        (const __attribute__((address_space(1))) void*)g,
        (__attribute__((address_space(3))) void*)l, 16, 0, 0);
}

// ---------------- prep kernel: W f32 -> bf16, pre-swizzled into d_ws --------
__global__ __launch_bounds__(256)
void prep_w_kernel(const float* __restrict__ wb0, const float* __restrict__ wc0,
                   const float* __restrict__ wb1, const float* __restrict__ wc1,
                   const float* __restrict__ wb2, const float* __restrict__ wc2,
                   unsigned char* __restrict__ ws) {
    int uid = blockIdx.x * 256 + threadIdx.x;   // one unit = 8 k-elems
    if (uid >= 23040) return;                   // 4608 + 9216 + 9216
    const float* wb; const float* wc; int C; size_t off; int uu;
    if (uid < 4608)       { wb = wb0; wc = wc0; C = 256; off = WOFF0; uu = uid; }
    else if (uid < 13824) { wb = wb1; wc = wc1; C = 512; off = WOFF1; uu = uid - 4608; }
    else                  { wb = wb2; wc = wc2; C = 512; off = WOFF2; uu = uid - 13824; }
    const int kunits = C / 8;
    const int row = uu / kunits;
    const int k   = (uu % kunits) * 8;
    const float* src = ((row < 64) ? (wb + row * C) : (wc + (row - 64) * C)) + k;
    const float4 f0 = *(const float4*)(src);
    const float4 f1 = *(const float4*)(src + 4);
    uint4 p;
    p.x = pack_bf16(f0.x, f0.y);
    p.y = pack_bf16(f0.z, f0.w);
    p.z = pack_bf16(f1.x, f1.y);
    p.w = pack_bf16(f1.z, f1.w);
    const int chunk = k >> 6;
    const int kg    = (k & 63) >> 3;
    *(uint4*)(ws + off + (size_t)chunk * WCHUNK_BYTES + swz(row, kg * 16)) = p;
}

// ---------------- main kernel ----------------------------------------------
template <int LVL>
__device__ __forceinline__ void run_level(
        int rb,
        const float* __restrict__ x,
        const unsigned char* __restrict__ wimg_all,
        const float* __restrict__ bbox, const float* __restrict__ bcls,
        float* __restrict__ out,
        unsigned char* s_w, unsigned char* s_x) {

    constexpr int    C      = (LVL == 0) ? 256 : 512;
    constexpr int    GW     = (LVL == 0) ? 80 : (LVL == 1 ? 40 : 20);
    constexpr int    HW     = GW * GW;
    constexpr int    AOFF   = (LVL == 0) ? 0 : (LVL == 1 ? 6400 : 8000);
    constexpr float  STRIDE = (LVL == 0) ? 8.0f : (LVL == 1 ? 16.0f : 32.0f);
    constexpr int    TPB    = (HW + 63) / 64;   // 64-anchor tiles per image
    constexpr size_t WOFF   = (LVL == 0) ? WOFF0 : (LVL == 1 ? WOFF1 : WOFF2);

    const int b    = rb / TPB;
    const int tile = rb % TPB;
    const int hw0  = tile * 64;
    const int nv   = (HW - hw0 < 64) ? (HW - hw0) : 64;  // valid anchors

    const int tid  = threadIdx.x;
    const int wv   = tid >> 6;        // wave 0..3
    const int lane = tid & 63;
    const int col  = lane & 15;       // MFMA n/col lane
    const int q4   = lane >> 4;       // MFMA row-quarter

    const float* xb = x + (size_t)b * C * HW;
    const unsigned char* wimg = wimg_all + WOFF;

    // X staging: thread -> (anchor = lane, k-group base = wave)
    const int anc  = lane;
    const int kgb  = wv;                              // 0..3
    const int ancc = (anc < nv) ? anc : (nv - 1);     // clamp OOB anchors
    const float* xcol = xb + hw0 + ancc;

    f32x4 acc[9];
#pragma unroll
    for (int m = 0; m < 9; ++m) acc[m] = (f32x4){0.f, 0.f, 0.f, 0.f};

    // ---- prologue: prefetch X chunk 0 into registers ----
    float xv[2][8];
#pragma unroll
    for (int i = 0; i < 2; ++i) {
        const float* p = xcol + (size_t)((kgb + 4 * i) * 8) * HW;
#pragma unroll
        for (int j = 0; j < 8; ++j) xv[i][j] = p[(size_t)j * HW];
    }

    const int nkc = C / 64;
    for (int kc = 0; kc < nkc; ++kc) {
        __syncthreads();   // barrier A: previous iteration's LDS reads done

        // ---- W: async DMA this chunk's pre-swizzled bf16 image -> s_w ----
        // linear copy: LDS dest = wave-uniform base + lane*16
#pragma unroll
        for (int i = 0; i < 5; ++i) {
            int u = tid + i * 256;
            if (u < 1152)
                gload_lds16(wimg + (size_t)kc * WCHUNK_BYTES + u * 16, s_w + u * 16);
        }

        // ---- X: pack prefetched regs -> s_x (transposed [anchor][k]) ----
#pragma unroll
        for (int i = 0; i < 2; ++i) {
            const int kg = kgb + 4 * i;
            uint4 q;
            q.x = pack_bf16(xv[i][0], xv[i][1]);
            q.y = pack_bf16(xv[i][2], xv[i][3]);
            q.z = pack_bf16(xv[i][4], xv[i][5]);
            q.w = pack_bf16(xv[i][6], xv[i][7]);
            *(uint4*)(s_x + swz(anc, kg * 16)) = q;
        }

        __syncthreads();   // barrier B: drains W DMA + X ds_writes

        // ---- issue next X chunk's loads; MFMA phase below covers latency ----
        if (kc + 1 < nkc) {
            const int k0n = (kc + 1) * 64;
#pragma unroll
            for (int i = 0; i < 2; ++i) {
                const float* p = xcol + (size_t)(k0n + (kgb + 4 * i) * 8) * HW;
#pragma unroll
                for (int j = 0; j < 8; ++j) xv[i][j] = p[(size_t)j * HW];
            }
        }

        // ---- MFMA: 2 k-steps of 32, 9 M-tiles x 1 N-tile per wave ----
#pragma unroll
        for (int ks = 0; ks < 2; ++ks) {
            const int kbyte = ks * 64 + q4 * 16;
            const bf16x8 bf = *(const bf16x8*)(s_x + swz(wv * 16 + col, kbyte));
#pragma unroll
            for (int m = 0; m < 9; ++m) {
                const bf16x8 af = *(const bf16x8*)(s_w + swz(m * 16 + col, kbyte));
                acc[m] = __builtin_amdgcn_mfma_f32_16x16x32_bf16(af, bf, acc[m], 0, 0, 0);
            }
        }
    }

    // ---- epilogue: in-register DFL decode + store ----
    // D layout (m89): value[r] = D[mtile*16 + q4*4 + r][col]
    float4 bcv[5];
#pragma unroll
    for (int m = 0; m < 5; ++m)
        bcv[m] = *(const float4*)(bcls + m * 16 + q4 * 4);

    const float LOG2E = 1.44269504088896f;

    const int alocal = wv * 16 + col;
    const bool valid = alocal < nv;
    const int hw = hw0 + alocal;

    float dist[4];
#pragma unroll
    for (int g = 0; g < 4; ++g) {
        const float4 bbv = *(const float4*)(bbox + g * 16 + q4 * 4);
        const float v0 = acc[g][0] + bbv.x;
        const float v1 = acc[g][1] + bbv.y;
        const float v2 = acc[g][2] + bbv.z;
        const float v3 = acc[g][3] + bbv.w;
        // softmax over 16 bins: 4 regs x 4 lanes (col, col+16, col+32, col+48)
        float mx = fmaxf(fmaxf(v0, v1), fmaxf(v2, v3));
        mx = fmaxf(mx, __shfl_xor(mx, 16));
        mx = fmaxf(mx, __shfl_xor(mx, 32));
        const float e0 = __builtin_amdgcn_exp2f((v0 - mx) * LOG2E);
        const float e1 = __builtin_amdgcn_exp2f((v1 - mx) * LOG2E);
        const float e2 = __builtin_amdgcn_exp2f((v2 - mx) * LOG2E);
        const float e3 = __builtin_amdgcn_exp2f((v3 - mx) * LOG2E);
        float s  = e0 + e1 + e2 + e3;
        float ws = e1 + 2.f * e2 + 3.f * e3 + (float)(q4 * 4) * s;
        s  += __shfl_xor(s, 16);
        s  += __shfl_xor(s, 32);
        ws += __shfl_xor(ws, 16);
        ws += __shfl_xor(ws, 32);
        dist[g] = ws / s;
    }

    if (valid) {
        const size_t obase = ((size_t)b * 8400 + AOFF + hw) * 84;
        if (q4 == 0) {
            const float ax = (float)(hw % GW) + 0.5f;
            const float ay = (float)(hw / GW) + 0.5f;
            f32x4 bx;
            bx[0] = (ax + 0.5f * (dist[2] - dist[0])) * STRIDE;
            bx[1] = (ay + 0.5f * (dist[3] - dist[1])) * STRIDE;
            bx[2] = (dist[0] + dist[2]) * STRIDE;
            bx[3] = (dist[1] + dist[3]) * STRIDE;
            *(f32x4*)(out + obase) = bx;
        }
#pragma unroll
        for (int m = 0; m < 5; ++m) {
            f32x4 v;
            v[0] = acc[m + 4][0] + bcv[m].x;
            v[1] = acc[m + 4][1] + bcv[m].y;
            v[2] = acc[m + 4][2] + bcv[m].z;
            v[3] = acc[m + 4][3] + bcv[m].w;
            *(f32x4*)(out + obase + 4 + m * 16 + q4 * 4) = v;
        }
    }
}

__global__ __launch_bounds__(NTHREADS, 6)
void UltralyticsDetect_kernel(
        const float* __restrict__ x0, const float* __restrict__ x1, const float* __restrict__ x2,
        const unsigned char* __restrict__ wimg,
        const float* __restrict__ bb0, const float* __restrict__ bc0,
        const float* __restrict__ bb1, const float* __restrict__ bc1,
        const float* __restrict__ bb2, const float* __restrict__ bc2,
        float* __restrict__ out) {

    __shared__ __align__(16) unsigned char s_w[144 * 64 * 2];  // 18 KiB
    __shared__ __align__(16) unsigned char s_x[64 * 64 * 2];   //  8 KiB

    const int bid = blockIdx.x;
    // Long (K=512) levels first so the tail is filled by short level-0 blocks:
    // level 1: 16 b * 25 tiles = 400 ; level 2: 16*7 = 112 ; level 0: 16*100 = 1600
    if (bid < 400) {
        run_level<1>(bid, x1, wimg, bb1, bc1, out, s_w, s_x);
    } else if (bid < 512) {
        run_level<2>(bid - 400, x2, wimg, bb2, bc2, out, s_w, s_x);
    } else {
        run_level<0>(bid - 512, x0, wimg, bb0, bc0, out, s_w, s_x);
    }
}

extern "C" void kernel_launch(void* const* d_in, const int* in_sizes, int n_in,
                              void* d_out, int out_size, void* d_ws, size_t ws_size,
                              hipStream_t stream) {
    const float* x0  = (const float*)d_in[0];
    const float* x1  = (const float*)d_in[1];
    const float* x2  = (const float*)d_in[2];
    const float* wb0 = (const float*)d_in[3];
    const float* bb0 = (const float*)d_in[4];
    const float* wc0 = (const float*)d_in[5];
    const float* bc0 = (const float*)d_in[6];
    const float* wb1 = (const float*)d_in[7];
    const float* bb1 = (const float*)d_in[8];
    const float* wc1 = (const float*)d_in[9];
    const float* bc1 = (const float*)d_in[10];
    const float* wb2 = (const float*)d_in[11];
    const float* bb2 = (const float*)d_in[12];
    const float* wc2 = (const float*)d_in[13];
    const float* bc2 = (const float*)d_in[14];

    unsigned char* wimg = (unsigned char*)d_ws;

    prep_w_kernel<<<90, 256, 0, stream>>>(wb0, wc0, wb1, wc1, wb2, wc2, wimg);

    UltralyticsDetect_kernel<<<2112, NTHREADS, 0, stream>>>(
        x0, x1, x2, wimg,
        bb0, bc0, bb1, bc1, bb2, bc2,
        (float*)d_out);
}

// Round 6
// 50.094 us; speedup vs baseline: 7.5245x; 1.1018x over previous
//
#include <hip/hip_runtime.h>

// UltralyticsDetect head, fused: per-level 1x1-conv GEMM (M=144, K=C, N=B*HW)
// in bf16 MFMA + in-register DFL softmax decode + output assembly.
// Output: (16, 8400, 84) f32.
//
// R6: X loads go DIRECTLY into MFMA B-fragments (no X LDS round-trip);
// double-buffered s_w with raw s_barrier + counted vmcnt(16) so the 16
// X prefetch loads stay in flight ACROSS barriers (T3/T4-lite); depth-2 X
// prefetch via named P/Q reg buffers (static indexing, rule #20);
// sched_barrier(0) pins issue order so the counted vmcnt is exact.

typedef __bf16 bf16x8 __attribute__((ext_vector_type(8)));
typedef float  f32x4  __attribute__((ext_vector_type(4)));

#define NTHREADS 256

// W image layout in d_ws: per level, C/64 chunks of 144 rows * 128 B,
// already swizzled; level byte offsets:
#define WOFF0 0
#define WOFF1 73728
#define WOFF2 221184
#define WCHUNK_BYTES 18432   // 144 * 128

// round-half-up f32 -> bf16, pack two into one u32 (a -> low16, b -> high16)
__device__ __forceinline__ unsigned int pack_bf16(float a, float b) {
    unsigned int ua = __builtin_bit_cast(unsigned int, a);
    unsigned int ub = __builtin_bit_cast(unsigned int, b);
    return ((ua + 0x8000u) >> 16) | ((ub + 0x8000u) & 0xffff0000u);
}

// LDS tile: row-major [row][64 bf16] = 128B rows, XOR-swizzled to kill the
// 32-way ds_read_b128 bank conflict (G4: byte ^= (row&7)<<4).
__device__ __forceinline__ int swz(int row, int kbyte) {
    return row * 128 + (kbyte ^ ((row & 7) << 4));
}

// async global->LDS, 16B per lane; LDS dest must be wave-uniform base + lane*16
__device__ __forceinline__ void gload_lds16(const void* g, void* l) {
    __builtin_amdgcn_global_load_lds(
        (const __attribute__((address_space(1))) void*)g,
        (__attribute__((address_space(3))) void*)l, 16, 0, 0);
}

// ---------------- prep kernel: W f32 -> bf16, pre-swizzled into d_ws --------
__global__ __launch_bounds__(256)
void prep_w_kernel(const float* __restrict__ wb0, const float* __restrict__ wc0,
                   const float* __restrict__ wb1, const float* __restrict__ wc1,
                   const float* __restrict__ wb2, const float* __restrict__ wc2,
                   unsigned char* __restrict__ ws) {
    int uid = blockIdx.x * 256 + threadIdx.x;   // one unit = 8 k-elems
    if (uid >= 23040) return;                   // 4608 + 9216 + 9216
    const float* wb; const float* wc; int C; size_t off; int uu;
    if (uid < 4608)       { wb = wb0; wc = wc0; C = 256; off = WOFF0; uu = uid; }
    else if (uid < 13824) { wb = wb1; wc = wc1; C = 512; off = WOFF1; uu = uid - 4608; }
    else                  { wb = wb2; wc = wc2; C = 512; off = WOFF2; uu = uid - 13824; }
    const int kunits = C / 8;
    const int row = uu / kunits;
    const int k   = (uu % kunits) * 8;
    const float* src = ((row < 64) ? (wb + row * C) : (wc + (row - 64) * C)) + k;
    const float4 f0 = *(const float4*)(src);
    const float4 f1 = *(const float4*)(src + 4);
    uint4 p;
    p.x = pack_bf16(f0.x, f0.y);
    p.y = pack_bf16(f0.z, f0.w);
    p.z = pack_bf16(f1.x, f1.y);
    p.w = pack_bf16(f1.z, f1.w);
    const int chunk = k >> 6;
    const int kg    = (k & 63) >> 3;
    *(uint4*)(ws + off + (size_t)chunk * WCHUNK_BYTES + swz(row, kg * 16)) = p;
}

// ---------------- main kernel ----------------------------------------------
template <int LVL>
__device__ __forceinline__ void run_level(
        int rb,
        const float* __restrict__ x,
        const unsigned char* __restrict__ wimg_all,
        const float* __restrict__ bbox, const float* __restrict__ bcls,
        float* __restrict__ out,
        unsigned char* s_w) {

    constexpr int    C      = (LVL == 0) ? 256 : 512;
    constexpr int    GW     = (LVL == 0) ? 80 : (LVL == 1 ? 40 : 20);
    constexpr int    HW     = GW * GW;
    constexpr int    AOFF   = (LVL == 0) ? 0 : (LVL == 1 ? 6400 : 8000);
    constexpr float  STRIDE = (LVL == 0) ? 8.0f : (LVL == 1 ? 16.0f : 32.0f);
    constexpr int    TPB    = (HW + 63) / 64;   // 64-anchor tiles per image
    constexpr size_t WOFF   = (LVL == 0) ? WOFF0 : (LVL == 1 ? WOFF1 : WOFF2);
    const int nkc = C / 64;

    const int b    = rb / TPB;
    const int tile = rb % TPB;
    const int hw0  = tile * 64;
    const int nv   = (HW - hw0 < 64) ? (HW - hw0) : 64;  // valid anchors

    const int tid  = threadIdx.x;
    const int wv   = tid >> 6;        // wave 0..3
    const int lane = tid & 63;
    const int col  = lane & 15;       // MFMA n/col lane
    const int q4   = lane >> 4;       // MFMA row-quarter

    const float* xb = x + (size_t)b * C * HW;
    const unsigned char* wimg = wimg_all + WOFF;

    // this lane's anchor (clamped for tail tiles)
    const int alocal = wv * 16 + col;
    const int ancc   = (alocal < nv) ? alocal : (nv - 1);
    const float* xanc = xb + hw0 + ancc;   // + k*HW indexes the k dimension

    f32x4 acc[9];
#pragma unroll
    for (int m = 0; m < 9; ++m) acc[m] = (f32x4){0.f, 0.f, 0.f, 0.f};

    float P[16], Q[16];   // depth-2 X prefetch buffers (static-indexed only)

    // X fragment load for chunk c: v[ks*8+j] = X[c*64 + ks*32 + q4*8 + j][anchor]
#define XLOAD(V, CC)                                                        \
    {                                                                       \
        const float* _p = xanc + (size_t)((CC) * 64 + q4 * 8) * HW;         \
        _Pragma("unroll")                                                   \
        for (int _ks = 0; _ks < 2; ++_ks)                                   \
            _Pragma("unroll")                                               \
            for (int _j = 0; _j < 8; ++_j)                                  \
                V[_ks * 8 + _j] = _p[(size_t)(_ks * 32 + _j) * HW];         \
    }

#define WDMA(CC, BUF)                                                       \
    {                                                                       \
        _Pragma("unroll")                                                   \
        for (int _i = 0; _i < 5; ++_i) {                                    \
            int _u = tid + _i * 256;                                        \
            if (_u < 1152)                                                  \
                gload_lds16(wimg + (size_t)(CC) * WCHUNK_BYTES + _u * 16,   \
                            s_w + (BUF) * WCHUNK_BYTES + _u * 16);          \
        }                                                                   \
    }

#define CVT(V, KS, DST)                                                     \
    {                                                                       \
        uint4 _q;                                                           \
        _q.x = pack_bf16(V[(KS) * 8 + 0], V[(KS) * 8 + 1]);                 \
        _q.y = pack_bf16(V[(KS) * 8 + 2], V[(KS) * 8 + 3]);                 \
        _q.z = pack_bf16(V[(KS) * 8 + 4], V[(KS) * 8 + 5]);                 \
        _q.w = pack_bf16(V[(KS) * 8 + 6], V[(KS) * 8 + 7]);                 \
        DST = __builtin_bit_cast(bf16x8, _q);                               \
    }

    // one chunk iteration; BUF = (KC)&1 as a literal
#define CHUNK_BODY(KC, V, BUF)                                              \
    {                                                                       \
        if ((KC) + 1 < nkc) WDMA((KC) + 1, 1 - (BUF));                      \
        __builtin_amdgcn_sched_barrier(0);                                  \
        bf16x8 _f0, _f1;                                                    \
        CVT(V, 0, _f0);                                                     \
        CVT(V, 1, _f1);                                                     \
        const bool _refill = (KC) + 2 < nkc;                                \
        if (_refill) XLOAD(V, (KC) + 2);                                    \
        __builtin_amdgcn_sched_barrier(0);                                  \
        _Pragma("unroll")                                                   \
        for (int _m = 0; _m < 9; ++_m) {                                    \
            const bf16x8 _a0 = *(const bf16x8*)(s_w + (BUF) * WCHUNK_BYTES  \
                                    + swz(_m * 16 + col, q4 * 16));         \
            acc[_m] = __builtin_amdgcn_mfma_f32_16x16x32_bf16(_a0, _f0,     \
                                                    acc[_m], 0, 0, 0);      \
            const bf16x8 _a1 = *(const bf16x8*)(s_w + (BUF) * WCHUNK_BYTES  \
                                    + swz(_m * 16 + col, 64 + q4 * 16));    \
            acc[_m] = __builtin_amdgcn_mfma_f32_16x16x32_bf16(_a1, _f1,     \
                                                    acc[_m], 0, 0, 0);      \
        }                                                                   \
        __builtin_amdgcn_sched_barrier(0);                                  \
        if (_refill) asm volatile("s_waitcnt vmcnt(16)" ::: "memory");      \
        else         asm volatile("s_waitcnt vmcnt(0)"  ::: "memory");      \
        __builtin_amdgcn_s_barrier();                                       \
        __builtin_amdgcn_sched_barrier(0);                                  \
    }

    // ---- prologue: W chunk 0 DMA + X chunks 0,1 into regs ----
    WDMA(0, 0);
    __builtin_amdgcn_sched_barrier(0);
    XLOAD(P, 0);
    XLOAD(Q, 1);
    __builtin_amdgcn_sched_barrier(0);
    asm volatile("s_waitcnt vmcnt(32)" ::: "memory");  // drain W(0), keep X(0),X(1)
    __builtin_amdgcn_s_barrier();
    __builtin_amdgcn_sched_barrier(0);

    for (int kc2 = 0; kc2 < nkc; kc2 += 2) {
        CHUNK_BODY(kc2,     P, 0);
        CHUNK_BODY(kc2 + 1, Q, 1);
    }

#undef CHUNK_BODY
#undef CVT
#undef WDMA
#undef XLOAD

    // ---- epilogue: in-register DFL decode + store ----
    // D layout (m89): value[r] = D[mtile*16 + q4*4 + r][col]
    float4 bcv[5];
#pragma unroll
    for (int m = 0; m < 5; ++m)
        bcv[m] = *(const float4*)(bcls + m * 16 + q4 * 4);

    const float LOG2E = 1.44269504088896f;

    const bool valid = alocal < nv;
    const int hw = hw0 + alocal;

    float dist[4];
#pragma unroll
    for (int g = 0; g < 4; ++g) {
        const float4 bbv = *(const float4*)(bbox + g * 16 + q4 * 4);
        const float v0 = acc[g][0] + bbv.x;
        const float v1 = acc[g][1] + bbv.y;
        const float v2 = acc[g][2] + bbv.z;
        const float v3 = acc[g][3] + bbv.w;
        // softmax over 16 bins: 4 regs x 4 lanes (col, col+16, col+32, col+48)
        float mx = fmaxf(fmaxf(v0, v1), fmaxf(v2, v3));
        mx = fmaxf(mx, __shfl_xor(mx, 16));
        mx = fmaxf(mx, __shfl_xor(mx, 32));
        const float e0 = __builtin_amdgcn_exp2f((v0 - mx) * LOG2E);
        const float e1 = __builtin_amdgcn_exp2f((v1 - mx) * LOG2E);
        const float e2 = __builtin_amdgcn_exp2f((v2 - mx) * LOG2E);
        const float e3 = __builtin_amdgcn_exp2f((v3 - mx) * LOG2E);
        float s  = e0 + e1 + e2 + e3;
        float ws = e1 + 2.f * e2 + 3.f * e3 + (float)(q4 * 4) * s;
        s  += __shfl_xor(s, 16);
        s  += __shfl_xor(s, 32);
        ws += __shfl_xor(ws, 16);
        ws += __shfl_xor(ws, 32);
        dist[g] = ws / s;
    }

    if (valid) {
        const size_t obase = ((size_t)b * 8400 + AOFF + hw) * 84;
        if (q4 == 0) {
            const float ax = (float)(hw % GW) + 0.5f;
            const float ay = (float)(hw / GW) + 0.5f;
            f32x4 bx;
            bx[0] = (ax + 0.5f * (dist[2] - dist[0])) * STRIDE;
            bx[1] = (ay + 0.5f * (dist[3] - dist[1])) * STRIDE;
            bx[2] = (dist[0] + dist[2]) * STRIDE;
            bx[3] = (dist[1] + dist[3]) * STRIDE;
            *(f32x4*)(out + obase) = bx;
        }
#pragma unroll
        for (int m = 0; m < 5; ++m) {
            f32x4 v;
            v[0] = acc[m + 4][0] + bcv[m].x;
            v[1] = acc[m + 4][1] + bcv[m].y;
            v[2] = acc[m + 4][2] + bcv[m].z;
            v[3] = acc[m + 4][3] + bcv[m].w;
            *(f32x4*)(out + obase + 4 + m * 16 + q4 * 4) = v;
        }
    }
}

__global__ __launch_bounds__(NTHREADS, 4)
void UltralyticsDetect_kernel(
        const float* __restrict__ x0, const float* __restrict__ x1, const float* __restrict__ x2,
        const unsigned char* __restrict__ wimg,
        const float* __restrict__ bb0, const float* __restrict__ bc0,
        const float* __restrict__ bb1, const float* __restrict__ bc1,
        const float* __restrict__ bb2, const float* __restrict__ bc2,
        float* __restrict__ out) {

    __shared__ __align__(16) unsigned char s_w[2 * WCHUNK_BYTES];  // 36 KiB dbuf

    const int bid = blockIdx.x;
    // Long (K=512) levels first so the tail is filled by short level-0 blocks:
    // level 1: 16 b * 25 tiles = 400 ; level 2: 16*7 = 112 ; level 0: 16*100 = 1600
    if (bid < 400) {
        run_level<1>(bid, x1, wimg, bb1, bc1, out, s_w);
    } else if (bid < 512) {
        run_level<2>(bid - 400, x2, wimg, bb2, bc2, out, s_w);
    } else {
        run_level<0>(bid - 512, x0, wimg, bb0, bc0, out, s_w);
    }
}

extern "C" void kernel_launch(void* const* d_in, const int* in_sizes, int n_in,
                              void* d_out, int out_size, void* d_ws, size_t ws_size,
                              hipStream_t stream) {
    const float* x0  = (const float*)d_in[0];
    const float* x1  = (const float*)d_in[1];
    const float* x2  = (const float*)d_in[2];
    const float* wb0 = (const float*)d_in[3];
    const float* bb0 = (const float*)d_in[4];
    const float* wc0 = (const float*)d_in[5];
    const float* bc0 = (const float*)d_in[6];
    const float* wb1 = (const float*)d_in[7];
    const float* bb1 = (const float*)d_in[8];
    const float* wc1 = (const float*)d_in[9];
    const float* bc1 = (const float*)d_in[10];
    const float* wb2 = (const float*)d_in[11];
    const float* bb2 = (const float*)d_in[12];
    const float* wc2 = (const float*)d_in[13];
    const float* bc2 = (const float*)d_in[14];

    unsigned char* wimg = (unsigned char*)d_ws;

    prep_w_kernel<<<90, 256, 0, stream>>>(wb0, wc0, wb1, wc1, wb2, wc2, wimg);

    UltralyticsDetect_kernel<<<2112, NTHREADS, 0, stream>>>(
        x0, x1, x2, wimg,
        bb0, bc0, bb1, bc1, bb2, bc2,
        (float*)d_out);
}